// Round 8
// baseline (928.714 us; speedup 1.0000x reference)
//
#include <hip/hip_runtime.h>

typedef unsigned short u16;
typedef unsigned int u32;
typedef unsigned long long u64;
typedef int   v4i  __attribute__((ext_vector_type(4)));
typedef short v8s  __attribute__((ext_vector_type(8)));
typedef float v2f  __attribute__((ext_vector_type(2)));
typedef float v16f __attribute__((ext_vector_type(16)));

#define B_ 256
#define T_ 120
#define E_ 256
#define H_ 1024
#define LDH 1032    // 1024 + 8 pad (u16); 32-row A-read form (low-conflict, measured)
#define LDX 264     // 256 + 8 pad

// ---- ws layout (bytes) ----
#define WS_WF   0                    // 10,485,760  (W fragments, bf16)
#define WS_X    10485760             // 15,728,640  (X (T,B,E) bf16)
#define WS_HS   26214400             // 62,914,560  (hs (T,B,H) bf16)
#define WS_BAR  89128960             // 122,880 (8 mgroups x 120 steps x 32 producer flags)

__device__ __forceinline__ u16 f2bf(float f) {
    union { float f; u32 u; } v; v.f = f;
    u32 r = v.u + 0x7fffu + ((v.u >> 16) & 1u);   // RNE
    return (u16)(r >> 16);
}
__device__ __forceinline__ float fsig(float x) {
    float t = __builtin_amdgcn_exp2f(-1.44269504f * x);
    return __builtin_amdgcn_rcpf(1.0f + t);
}
__device__ __forceinline__ float ftanh_(float x) {
    float xc = fminf(8.0f, fmaxf(-8.0f, x));
    float t = __builtin_amdgcn_exp2f(2.88539008f * xc);
    return (t - 1.0f) * __builtin_amdgcn_rcpf(t + 1.0f);
}
__device__ __forceinline__ void gl_lds16(const void* g, void* l) {
    __builtin_amdgcn_global_load_lds(
        (const __attribute__((address_space(1))) void*)g,
        (__attribute__((address_space(3))) void*)l, 16, 0, 0);
}

// ---------------- P1 (merged): W transform + embedding gather + out=b2 init ----------------
// W part (blocks 0..1279): 32x32x16 B-frags. cid = nc*8 + g*2 + khalf; frag f 0..39,
// s = 2f+khalf; elem (l,j) = W[16s + (l>>5)*8 + j][g*1024 + nc*32 + (l&31)].
__global__ void prep_all(const float* __restrict__ W, u16* __restrict__ Wf,
                         const int* __restrict__ tokens, const float* __restrict__ emb,
                         u16* __restrict__ X, const float* __restrict__ b2,
                         float* __restrict__ out) {
    __shared__ u16 tile[32 * 136];
    int bid = blockIdx.x;
    int tid = threadIdx.x;
    if (bid < 1280) {
        int cid = bid / 5, fo = bid % 5;
        int kh  = cid & 1, g = (cid >> 1) & 3, nc = cid >> 3;
        int colbase = g * 1024 + nc * 32;
        int c = tid & 31, r = tid >> 5;       // r 0..7
#pragma unroll
        for (int fl = 0; fl < 8; ++fl) {
            int k0 = (2 * (fo * 8 + fl) + kh) * 16;
#pragma unroll
            for (int rr = 0; rr < 2; ++rr) {
                int row = r + rr * 8;         // 0..15
                float v = W[(size_t)(k0 + row) * 4096 + colbase + c];
                tile[c * 136 + fl * 16 + row] = f2bf(v);
            }
        }
        __syncthreads();
        int lane = tid & 63;
#pragma unroll
        for (int pass = 0; pass < 2; ++pass) {
            int fl = (tid >> 6) + pass * 4;
            v4i o = *(const v4i*)&tile[(lane & 31) * 136 + fl * 16 + ((lane >> 5) << 3)];
            *(v4i*)(Wf + (((size_t)(cid * 40 + fo * 8 + fl)) << 9) + lane * 8) = o;
        }
    } else if (bid < 5120) {
        int v   = (bid - 1280) * 256 + tid;           // < 983040
        int e8  = v & 31;
        int row = v >> 5;                             // t*256 + b
        int t = row >> 8, b = row & 255;
        int tok = tokens[b * T_ + t];
        const float* src = emb + (size_t)tok * E_ + e8 * 8;
        u16 o[8];
#pragma unroll
        for (int j = 0; j < 8; ++j) o[j] = f2bf(src[j]);
        *(v4i*)(X + (size_t)row * E_ + e8 * 8) = *(v4i*)o;
    } else {
        int row = (bid - 5120) * 256 + tid;           // < 30720
        if (row < B_ * T_) {
#pragma unroll
            for (int c = 0; c < 5; ++c) out[(size_t)row * 5 + c] = b2[c];
        }
    }
}

// ---------------- main persistent LSTM kernel (R4 structure) ----------------
// 256 blocks x 512 threads. Block (mchunk=bid&7, nc=bid>>3). Wave (g=wv>>1,
// khalf=wv&1): 32x32 gate tile over K-half. W pinned (160 VGPR).
// Handshake: 32 per-producer flag WORDS per (mgroup,step) — parallel relaxed
// stores (no RMW serialization at LLC) + 32-lane parallel poll.
// Projection folded in: per-step partial h.U accumulated to out via atomics,
// issued in the post-flag slack window.
__global__ __launch_bounds__(512, 2) void lstm_main(
    const u16* __restrict__ Wf, const u16* __restrict__ X,
    const float* __restrict__ b_lstm, u16* __restrict__ hs,
    u32* __restrict__ bar, const float* __restrict__ U,
    float* __restrict__ out) {

    __shared__ u16  hbuf[32 * LDH];           // 66,048 B
    __shared__ u16  xbuf[32 * LDX];           // 16,896 B
    __shared__ float gates[2 * 4 * 32 * 34];  // 34,816 B
    __shared__ float bias[128];

    const int tid   = threadIdx.x;
    const int lane  = tid & 63;
    const int wv    = tid >> 6;
    const int g     = wv >> 1;
    const int khalf = wv & 1;
    const int bid   = blockIdx.x;
    const int mchunk = bid & 7;
    const int nc    = bid >> 3;
    const int m0    = mchunk << 5;

    if (tid < 128) bias[tid] = b_lstm[(tid >> 5) * H_ + (nc << 5) + (tid & 31)];

    // ---- resident W fragments: 40 x v8s = 160 VGPR, pinned ----
    v8s Wr[40];
    {
        const v4i* wsrc = (const v4i*)(Wf + (size_t)(nc * 8 + g * 2 + khalf) * 20480);
#pragma unroll
        for (int f = 0; f < 40; ++f)
            Wr[f] = __builtin_bit_cast(v8s, wsrc[f * 64 + lane]);
    }
#pragma unroll
    for (int f = 0; f < 40; ++f) asm volatile("" : "+v"(Wr[f]));

    // ---- per-thread U rows for folded projection (rows nc*32+cn2, +1) ----
    const int cm  = tid >> 4;
    const int cn2 = (tid & 15) << 1;
    float Ur[2][5];
#pragma unroll
    for (int q = 0; q < 2; ++q)
#pragma unroll
        for (int c = 0; c < 5; ++c)
            Ur[q][c] = U[(size_t)((nc << 5) + cn2 + q) * 5 + c];

    // ---- stage X_0 ----
    {
        const v4i* xs = (const v4i*)(X + (size_t)m0 * E_);
#pragma unroll
        for (int i = 0; i < 2; ++i) {
            int idx = tid + i * 512;
            int r = idx >> 5, c8 = idx & 31;
            *(v4i*)&xbuf[r * LDX + c8 * 8] = xs[r * 32 + c8];
        }
    }
    __syncthreads();

    const u16* Ax = &xbuf[(lane & 31) * LDX + ((lane >> 5) << 3)];
    const u16* Ah = &hbuf[(lane & 31) * LDH + ((lane >> 5) << 3)];

    // ---- x-part MFMA for t=0 ----
    v16f acc = {0,0,0,0,0,0,0,0,0,0,0,0,0,0,0,0};
#pragma unroll
    for (int f = 0; f < 8; ++f) {
        v8s a = *(const v8s*)(Ax + (2 * f + khalf) * 16);
        acc = __builtin_amdgcn_mfma_f32_32x32x16_bf16(a, Wr[f], acc, 0, 0, 0);
    }

    float cst[2] = {0.f, 0.f};
    u32* hs32 = (u32*)hs;

    for (int t = 0; t < T_; ++t) {
        if (t > 0) {
            // ---- wait h_{t-1}: 32 lanes poll 32 per-producer flags in parallel ----
            if (tid < 32) {
                u32* p = &bar[(size_t)((mchunk * T_ + (t - 1)) << 5) + tid];
                while (!__hip_atomic_load(p, __ATOMIC_RELAXED, __HIP_MEMORY_SCOPE_AGENT))
                    __builtin_amdgcn_s_sleep(1);
            }
            __syncthreads();
            // ---- issue async h loads: wave wv -> rows [wv*4,+4), low then high half ----
            {
                const u16* srcb = hs + ((size_t)(t - 1) * B_ + m0) * H_;
                const int r0 = wv << 2;
#pragma unroll
                for (int i = 0; i < 4; ++i)
                    gl_lds16(srcb + (size_t)(r0 + i) * H_ + lane * 8,
                             &hbuf[(r0 + i) * LDH]);
#pragma unroll
                for (int i = 0; i < 4; ++i)
                    gl_lds16(srcb + (size_t)(r0 + i) * H_ + 512 + lane * 8,
                             &hbuf[(r0 + i) * LDH + 512]);
            }
            // ---- chunk A: h cols [0,512) (f 8..23) ----
            asm volatile("s_waitcnt vmcnt(4)\n\ts_barrier" ::: "memory");
#pragma unroll
            for (int f = 8; f < 24; ++f) {
                v8s a = *(const v8s*)(Ah + (2 * f + khalf) * 16 - 256);
                acc = __builtin_amdgcn_mfma_f32_32x32x16_bf16(a, Wr[f], acc, 0, 0, 0);
            }
            // ---- chunk B: h cols [512,1024) (f 24..39) ----
            asm volatile("s_waitcnt vmcnt(0)\n\ts_barrier" ::: "memory");
#pragma unroll
            for (int f = 24; f < 40; ++f) {
                v8s a = *(const v8s*)(Ah + (2 * f + khalf) * 16 - 256);
                acc = __builtin_amdgcn_mfma_f32_32x32x16_bf16(a, Wr[f], acc, 0, 0, 0);
            }
        }

        // ---- partials -> LDS: C/D col=lane&31, row=(reg&3)+8*(reg>>2)+4*(lane>>5) ----
        {
            float* gb = &gates[(khalf * 4 + g) * 1088];
            int col = lane & 31, rq = (lane >> 5) << 2;
#pragma unroll
            for (int reg = 0; reg < 16; ++reg) {
                int row = (reg & 3) + ((reg >> 2) << 3) + rq;
                gb[row * 34 + col] = acc[reg];
            }
        }
        __syncthreads();

        // ---- prefetch X_{t+1} (overlaps cell transcendentals) ----
        if (t + 1 < T_) {
            const v4i* xs = (const v4i*)(X + ((size_t)(t + 1) * B_ + m0) * E_);
#pragma unroll
            for (int i = 0; i < 2; ++i) {
                int idx = tid + i * 512;
                int r = idx >> 5, c8 = idx & 31;
                *(v4i*)&xbuf[r * LDX + c8 * 8] = xs[r * 32 + c8];
            }
        }

        // ---- cell math: sum K-halves, bias, activations ----
        float hh[2];
        {
            v2f zz[4];
#pragma unroll
            for (int gg = 0; gg < 4; ++gg) {
                v2f a = *(const v2f*)&gates[gg * 1088 + cm * 34 + cn2];
                v2f b = *(const v2f*)&gates[(4 + gg) * 1088 + cm * 34 + cn2];
                zz[gg].x = a.x + b.x; zz[gg].y = a.y + b.y;
            }
            u32 hpack = 0;
#pragma unroll
            for (int q = 0; q < 2; ++q) {
                int n = cn2 + q;
                float ip = zz[0][q] + bias[n];
                float jp = zz[1][q] + bias[32 + n];
                float fp = zz[2][q] + bias[64 + n] + 1.0f;
                float op = zz[3][q] + bias[96 + n];
                float cc = fsig(fp) * cst[q] + fsig(ip) * ftanh_(jp);
                cst[q] = cc;
                hh[q] = fsig(op) * ftanh_(cc);
                hpack |= ((u32)f2bf(hh[q])) << (16 * q);
            }
            __hip_atomic_store(&hs32[((size_t)t * B_ + m0 + cm) * 512 + (nc << 4) + (tid & 15)],
                               hpack, __ATOMIC_RELAXED, __HIP_MEMORY_SCOPE_AGENT);
        }

        // ---- release: drain own stores, rendezvous, then ONE parallel flag store ----
        asm volatile("s_waitcnt vmcnt(0)" ::: "memory");
        __syncthreads();
        if (t + 1 < T_) {
            if (tid == 0)
                __hip_atomic_store(&bar[(size_t)((mchunk * T_ + t) << 5) + nc], 1u,
                                   __ATOMIC_RELAXED, __HIP_MEMORY_SCOPE_AGENT);
            // ---- x-part MFMA for t+1 (handshake cover) ----
#pragma unroll
            for (int reg = 0; reg < 16; ++reg) acc[reg] = 0.f;
#pragma unroll
            for (int f = 0; f < 8; ++f) {
                v8s a = *(const v8s*)(Ax + (2 * f + khalf) * 16);
                acc = __builtin_amdgcn_mfma_f32_32x32x16_bf16(a, Wr[f], acc, 0, 0, 0);
            }
        }

        // ---- folded projection: out[m0+cm, t, :] += h(cols nc*32..+32) . U ----
        {
            float p[5];
#pragma unroll
            for (int c = 0; c < 5; ++c)
                p[c] = hh[0] * Ur[0][c] + hh[1] * Ur[1][c];
#pragma unroll
            for (int c = 0; c < 5; ++c) {
                p[c] += __shfl_xor(p[c], 1, 16);
                p[c] += __shfl_xor(p[c], 2, 16);
                p[c] += __shfl_xor(p[c], 4, 16);
                p[c] += __shfl_xor(p[c], 8, 16);
            }
            if ((tid & 15) == 0) {
                float* dst = &out[((size_t)(m0 + cm) * T_ + t) * 5];
#pragma unroll
                for (int c = 0; c < 5; ++c)
                    atomicAdd(dst + c, p[c]);
            }
        }
    }
}

extern "C" void kernel_launch(void* const* d_in, const int* in_sizes, int n_in,
                              void* d_out, int out_size, void* d_ws, size_t ws_size,
                              hipStream_t stream) {
    const int*   tokens = (const int*)d_in[0];
    const float* emb    = (const float*)d_in[1];
    const float* W      = (const float*)d_in[2];
    const float* b_l    = (const float*)d_in[3];
    const float* U      = (const float*)d_in[4];
    const float* b2     = (const float*)d_in[5];
    float* out = (float*)d_out;

    char* ws = (char*)d_ws;
    u16* Wf  = (u16*)(ws + WS_WF);
    u16* X   = (u16*)(ws + WS_X);
    u16* hs  = (u16*)(ws + WS_HS);
    u32* bar = (u32*)(ws + WS_BAR);

    hipMemsetAsync(bar, 0, 8 * T_ * 32 * sizeof(u32), stream);
    prep_all<<<5240, 256, 0, stream>>>(W, Wf, tokens, emb, X, b2, out);
    lstm_main<<<256, 512, 0, stream>>>(Wf, X, b_l, hs, bar, U, out);
}

// Round 9
// 615.207 us; speedup vs baseline: 1.5096x; 1.5096x over previous
//
#include <hip/hip_runtime.h>

typedef unsigned short u16;
typedef unsigned int u32;
typedef int   v4i  __attribute__((ext_vector_type(4)));
typedef short v8s  __attribute__((ext_vector_type(8)));
typedef float v2f  __attribute__((ext_vector_type(2)));
typedef float v16f __attribute__((ext_vector_type(16)));

#define B_ 256
#define T_ 120
#define E_ 256
#define H_ 1024
#define LDH 1032    // 1024 + 8 pad (u16); 32-row A-read form (low-conflict, measured R4)
#define LDX 264     // 256 + 8 pad

// ---- ws layout (bytes) ----
#define WS_WF   0                    // 10,485,760  (W fragments, bf16)
#define WS_X    10485760             // 15,728,640  (X (T,B,E) bf16)
#define WS_HS   26214400             // 62,914,560  (hs (T,B,H) bf16)
#define WS_BAR  89128960             // 122,880 (8 mgroups x 120 steps x 32 producer flags)

__device__ __forceinline__ u16 f2bf(float f) {
    union { float f; u32 u; } v; v.f = f;
    u32 r = v.u + 0x7fffu + ((v.u >> 16) & 1u);   // RNE
    return (u16)(r >> 16);
}
__device__ __forceinline__ float bf2f(u16 u) {
    union { u32 u; float f; } v; v.u = ((u32)u) << 16; return v.f;
}
__device__ __forceinline__ float fsig(float x) {
    float t = __builtin_amdgcn_exp2f(-1.44269504f * x);
    return __builtin_amdgcn_rcpf(1.0f + t);
}
__device__ __forceinline__ float ftanh_(float x) {
    float xc = fminf(8.0f, fmaxf(-8.0f, x));
    float t = __builtin_amdgcn_exp2f(2.88539008f * xc);
    return (t - 1.0f) * __builtin_amdgcn_rcpf(t + 1.0f);
}
__device__ __forceinline__ void gl_lds16(const void* g, void* l) {
    __builtin_amdgcn_global_load_lds(
        (const __attribute__((address_space(1))) void*)g,
        (__attribute__((address_space(3))) void*)l, 16, 0, 0);
}

// ---------------- P1 (merged): W transform + embedding gather + bar zero ----------------
// W part (blocks 0..1279): 32x32x16 B-frags. cid = nc*8 + g*2 + khalf; frag f 0..39,
// s = 2f+khalf; elem (l,j) = W[16s + (l>>5)*8 + j][g*1024 + nc*32 + (l&31)].
__global__ void prep_all(const float* __restrict__ W, u16* __restrict__ Wf,
                         const int* __restrict__ tokens, const float* __restrict__ emb,
                         u16* __restrict__ X, u32* __restrict__ bar) {
    __shared__ u16 tile[32 * 136];
    int bid = blockIdx.x;
    int tid = threadIdx.x;
    if (bid < 1280) {
        int cid = bid / 5, fo = bid % 5;
        int kh  = cid & 1, g = (cid >> 1) & 3, nc = cid >> 3;
        int colbase = g * 1024 + nc * 32;
        int c = tid & 31, r = tid >> 5;       // r 0..7
#pragma unroll
        for (int fl = 0; fl < 8; ++fl) {
            int k0 = (2 * (fo * 8 + fl) + kh) * 16;
#pragma unroll
            for (int rr = 0; rr < 2; ++rr) {
                int row = r + rr * 8;         // 0..15
                float v = W[(size_t)(k0 + row) * 4096 + colbase + c];
                tile[c * 136 + fl * 16 + row] = f2bf(v);
            }
        }
        __syncthreads();
        int lane = tid & 63;
#pragma unroll
        for (int pass = 0; pass < 2; ++pass) {
            int fl = (tid >> 6) + pass * 4;
            v4i o = *(const v4i*)&tile[(lane & 31) * 136 + fl * 16 + ((lane >> 5) << 3)];
            *(v4i*)(Wf + (((size_t)(cid * 40 + fo * 8 + fl)) << 9) + lane * 8) = o;
        }
    } else if (bid < 5120) {
        int v   = (bid - 1280) * 256 + tid;           // < 983040
        int e8  = v & 31;
        int row = v >> 5;                             // t*256 + b
        int t = row >> 8, b = row & 255;
        int tok = tokens[b * T_ + t];
        const float* src = emb + (size_t)tok * E_ + e8 * 8;
        u16 o[8];
#pragma unroll
        for (int j = 0; j < 8; ++j) o[j] = f2bf(src[j]);
        *(v4i*)(X + (size_t)row * E_ + e8 * 8) = *(v4i*)o;
    } else {
        int idx = (bid - 5120) * 256 + tid;           // < 30720
        bar[idx] = 0u;                                // kernel-end release flushes to LLC
    }
}

// ---------------- main persistent LSTM kernel (R4 structure, 511us-proven) ----------------
// 256 blocks x 512 threads. Block (mchunk=bid&7, nc=bid>>3). Wave (g=wv>>1,
// khalf=wv&1): 32x32 gate tile over K-half. W pinned (160 VGPR).
// ONLY change vs R4: handshake = 32 per-producer flag WORDS per (mgroup,step)
// (parallel relaxed stores, no RMW chain at the LLC) + 32-lane parallel poll.
__global__ __launch_bounds__(512, 2) void lstm_main(
    const u16* __restrict__ Wf, const u16* __restrict__ X,
    const float* __restrict__ b_lstm, u16* __restrict__ hs,
    u32* __restrict__ bar) {

    __shared__ u16  hbuf[32 * LDH];           // 66,048 B
    __shared__ u16  xbuf[32 * LDX];           // 16,896 B
    __shared__ float gates[2 * 4 * 32 * 34];  // 34,816 B
    __shared__ float bias[128];

    const int tid   = threadIdx.x;
    const int lane  = tid & 63;
    const int wv    = tid >> 6;
    const int g     = wv >> 1;
    const int khalf = wv & 1;
    const int bid   = blockIdx.x;
    const int mchunk = bid & 7;
    const int nc    = bid >> 3;
    const int m0    = mchunk << 5;

    if (tid < 128) bias[tid] = b_lstm[(tid >> 5) * H_ + (nc << 5) + (tid & 31)];

    // ---- resident W fragments: 40 x v8s = 160 VGPR, pinned ----
    v8s Wr[40];
    {
        const v4i* wsrc = (const v4i*)(Wf + (size_t)(nc * 8 + g * 2 + khalf) * 20480);
#pragma unroll
        for (int f = 0; f < 40; ++f)
            Wr[f] = __builtin_bit_cast(v8s, wsrc[f * 64 + lane]);
    }
#pragma unroll
    for (int f = 0; f < 40; ++f) asm volatile("" : "+v"(Wr[f]));

    // ---- stage X_0 ----
    {
        const v4i* xs = (const v4i*)(X + (size_t)m0 * E_);
#pragma unroll
        for (int i = 0; i < 2; ++i) {
            int idx = tid + i * 512;
            int r = idx >> 5, c8 = idx & 31;
            *(v4i*)&xbuf[r * LDX + c8 * 8] = xs[r * 32 + c8];
        }
    }
    __syncthreads();

    const u16* Ax = &xbuf[(lane & 31) * LDX + ((lane >> 5) << 3)];
    const u16* Ah = &hbuf[(lane & 31) * LDH + ((lane >> 5) << 3)];

    // ---- x-part MFMA for t=0 ----
    v16f acc = {0,0,0,0,0,0,0,0,0,0,0,0,0,0,0,0};
#pragma unroll
    for (int f = 0; f < 8; ++f) {
        v8s a = *(const v8s*)(Ax + (2 * f + khalf) * 16);
        acc = __builtin_amdgcn_mfma_f32_32x32x16_bf16(a, Wr[f], acc, 0, 0, 0);
    }

    float cst[2] = {0.f, 0.f};
    const int cm  = tid >> 4;
    const int cn2 = (tid & 15) << 1;
    u32* hs32 = (u32*)hs;

    for (int t = 0; t < T_; ++t) {
        if (t > 0) {
            // ---- wait h_{t-1}: 32 lanes poll the 32 per-producer flags in parallel ----
            if (tid < 32) {
                u32* p = &bar[(size_t)((mchunk * T_ + (t - 1)) << 5) + tid];
                while (!__hip_atomic_load(p, __ATOMIC_RELAXED, __HIP_MEMORY_SCOPE_AGENT))
                    __builtin_amdgcn_s_sleep(1);
            }
            __syncthreads();
            // ---- issue async h loads: wave wv -> rows [wv*4,+4), low then high half ----
            {
                const u16* srcb = hs + ((size_t)(t - 1) * B_ + m0) * H_;
                const int r0 = wv << 2;
#pragma unroll
                for (int i = 0; i < 4; ++i)
                    gl_lds16(srcb + (size_t)(r0 + i) * H_ + lane * 8,
                             &hbuf[(r0 + i) * LDH]);
#pragma unroll
                for (int i = 0; i < 4; ++i)
                    gl_lds16(srcb + (size_t)(r0 + i) * H_ + 512 + lane * 8,
                             &hbuf[(r0 + i) * LDH + 512]);
            }
            // ---- chunk A: h cols [0,512) (f 8..23) ----
            asm volatile("s_waitcnt vmcnt(4)\n\ts_barrier" ::: "memory");
#pragma unroll
            for (int f = 8; f < 24; ++f) {
                v8s a = *(const v8s*)(Ah + (2 * f + khalf) * 16 - 256);
                acc = __builtin_amdgcn_mfma_f32_32x32x16_bf16(a, Wr[f], acc, 0, 0, 0);
            }
            // ---- chunk B: h cols [512,1024) (f 24..39) ----
            asm volatile("s_waitcnt vmcnt(0)\n\ts_barrier" ::: "memory");
#pragma unroll
            for (int f = 24; f < 40; ++f) {
                v8s a = *(const v8s*)(Ah + (2 * f + khalf) * 16 - 256);
                acc = __builtin_amdgcn_mfma_f32_32x32x16_bf16(a, Wr[f], acc, 0, 0, 0);
            }
        }

        // ---- partials -> LDS: C/D col=lane&31, row=(reg&3)+8*(reg>>2)+4*(lane>>5) ----
        {
            float* gb = &gates[(khalf * 4 + g) * 1088];
            int col = lane & 31, rq = (lane >> 5) << 2;
#pragma unroll
            for (int reg = 0; reg < 16; ++reg) {
                int row = (reg & 3) + ((reg >> 2) << 3) + rq;
                gb[row * 34 + col] = acc[reg];
            }
        }
        __syncthreads();

        // ---- prefetch X_{t+1} (overlaps cell transcendentals) ----
        if (t + 1 < T_) {
            const v4i* xs = (const v4i*)(X + ((size_t)(t + 1) * B_ + m0) * E_);
#pragma unroll
            for (int i = 0; i < 2; ++i) {
                int idx = tid + i * 512;
                int r = idx >> 5, c8 = idx & 31;
                *(v4i*)&xbuf[r * LDX + c8 * 8] = xs[r * 32 + c8];
            }
        }

        // ---- cell math: sum K-halves, bias, activations ----
        u32 hpack = 0;
        {
            v2f zz[4];
#pragma unroll
            for (int gg = 0; gg < 4; ++gg) {
                v2f a = *(const v2f*)&gates[gg * 1088 + cm * 34 + cn2];
                v2f b = *(const v2f*)&gates[(4 + gg) * 1088 + cm * 34 + cn2];
                zz[gg].x = a.x + b.x; zz[gg].y = a.y + b.y;
            }
#pragma unroll
            for (int q = 0; q < 2; ++q) {
                int n = cn2 + q;
                float ip = zz[0][q] + bias[n];
                float jp = zz[1][q] + bias[32 + n];
                float fp = zz[2][q] + bias[64 + n] + 1.0f;
                float op = zz[3][q] + bias[96 + n];
                float cc = fsig(fp) * cst[q] + fsig(ip) * ftanh_(jp);
                cst[q] = cc;
                hpack |= ((u32)f2bf(fsig(op) * ftanh_(cc))) << (16 * q);
            }
        }
        __hip_atomic_store(&hs32[((size_t)t * B_ + m0 + cm) * 512 + (nc << 4) + (tid & 15)],
                           hpack, __ATOMIC_RELAXED, __HIP_MEMORY_SCOPE_AGENT);

        if (t + 1 < T_) {
            // ---- release: drain own stores, rendezvous, ONE parallel flag store ----
            asm volatile("s_waitcnt vmcnt(0)" ::: "memory");
            __syncthreads();
            if (tid == 0)
                __hip_atomic_store(&bar[(size_t)((mchunk * T_ + t) << 5) + nc], 1u,
                                   __ATOMIC_RELAXED, __HIP_MEMORY_SCOPE_AGENT);
            // ---- x-part MFMA for t+1 (handshake cover) ----
#pragma unroll
            for (int reg = 0; reg < 16; ++reg) acc[reg] = 0.f;
#pragma unroll
            for (int f = 0; f < 8; ++f) {
                v8s a = *(const v8s*)(Ax + (2 * f + khalf) * 16);
                acc = __builtin_amdgcn_mfma_f32_32x32x16_bf16(a, Wr[f], acc, 0, 0, 0);
            }
        }
    }
}

// ---------------- P3: preds = hs @ U + b2 (64 rows/block; U staged once) ----------------
__global__ void proj_kernel(const u16* __restrict__ hs, const float* __restrict__ U,
                            const float* __restrict__ b2, float* __restrict__ out) {
    __shared__ float Ul[H_ * 5];
    int tid = threadIdx.x;
    for (int i = tid; i < H_ * 5; i += 256) Ul[i] = U[i];
    __syncthreads();
    int wv = tid >> 6, lane = tid & 63;
#pragma unroll 1
    for (int i = 0; i < 16; ++i) {
        int row = blockIdx.x * 64 + wv * 16 + i;   // t*256 + b, < 30720
        int t = row >> 8, b = row & 255;
        const v4i* hp = (const v4i*)(hs + (size_t)row * H_);
        float p[5] = {0.f, 0.f, 0.f, 0.f, 0.f};
#pragma unroll
        for (int half = 0; half < 2; ++half) {
            v4i hv = hp[lane * 2 + half];
            u16 us[8];
            *(v4i*)us = hv;
#pragma unroll
            for (int j = 0; j < 8; ++j) {
                float hf = bf2f(us[j]);
                int k = lane * 16 + half * 8 + j;
#pragma unroll
                for (int c = 0; c < 5; ++c) p[c] += hf * Ul[k * 5 + c];
            }
        }
#pragma unroll
        for (int c = 0; c < 5; ++c)
            for (int off = 32; off > 0; off >>= 1)
                p[c] += __shfl_down(p[c], off, 64);
        if (lane == 0) {
#pragma unroll
            for (int c = 0; c < 5; ++c)
                out[((size_t)b * T_ + t) * 5 + c] = p[c] + b2[c];
        }
    }
}

extern "C" void kernel_launch(void* const* d_in, const int* in_sizes, int n_in,
                              void* d_out, int out_size, void* d_ws, size_t ws_size,
                              hipStream_t stream) {
    const int*   tokens = (const int*)d_in[0];
    const float* emb    = (const float*)d_in[1];
    const float* W      = (const float*)d_in[2];
    const float* b_l    = (const float*)d_in[3];
    const float* U      = (const float*)d_in[4];
    const float* b2     = (const float*)d_in[5];
    float* out = (float*)d_out;

    char* ws = (char*)d_ws;
    u16* Wf  = (u16*)(ws + WS_WF);
    u16* X   = (u16*)(ws + WS_X);
    u16* hs  = (u16*)(ws + WS_HS);
    u32* bar = (u32*)(ws + WS_BAR);

    prep_all<<<5240, 256, 0, stream>>>(W, Wf, tokens, emb, X, bar);
    lstm_main<<<256, 512, 0, stream>>>(Wf, X, b_l, hs, bar);
    proj_kernel<<<480, 256, 0, stream>>>(hs, U, b2, out);
}